// Round 1
// baseline (208.952 us; speedup 1.0000x reference)
//
#include <hip/hip_runtime.h>
#include <stdint.h>
#include <stddef.h>

typedef __attribute__((ext_vector_type(8))) short short8;
typedef __attribute__((ext_vector_type(4))) float f32x4;
typedef __attribute__((ext_vector_type(4))) short short4v;

__device__ __forceinline__ short f2bf(float f) {
  unsigned u = __builtin_bit_cast(unsigned, f);
  u = (u + 0x7fffu + ((u >> 16) & 1u)) >> 16;
  return (short)u;
}

__device__ __forceinline__ void gload16(const void* g, void* l) {
  __builtin_amdgcn_global_load_lds(
      (const __attribute__((address_space(1))) unsigned int*)g,
      (__attribute__((address_space(3))) unsigned int*)l, 16, 0, 0);
}

// ---------------- conversion kernels ----------------

// x (4096x768 f32) -> bf16, vectorized. 786432 threads, 4 elems each.
__global__ __launch_bounds__(256)
void cvt_x_k(const float* __restrict__ in, short* __restrict__ out) {
  const int i = blockIdx.x * 256 + threadIdx.x;
  const float4 v = ((const float4*)in)[i];
  short4v o;
  o.x = f2bf(v.x); o.y = f2bf(v.y); o.z = f2bf(v.z); o.w = f2bf(v.w);
  *(short4v*)(out + (size_t)i * 4) = o;
}

// node_w1 (63,768,16) -> BTn[(n*16+h)][i], padded to 1024 rows with zeros.
__global__ __launch_bounds__(256)
void cvt_btn_k(const float* __restrict__ nw1, short* __restrict__ BTn) {
  const int idx = blockIdx.x * 256 + threadIdx.x;  // 1024*768 = 786432
  const int i = idx % 768;
  const int nh = idx / 768;
  float v = 0.f;
  if (nh < 1008) v = nw1[((size_t)(nh >> 4) * 768 + i) * 16 + (nh & 15)];
  BTn[idx] = f2bf(v);
}

// leaf_w1 (64,768,128) -> BT1[(l*128+h)][i]  (LDS tile transpose, coalesced both sides)
__global__ __launch_bounds__(256)
void cvt_bt1_k(const float* __restrict__ lw1, short* __restrict__ BT1) {
  __shared__ float tile[64][65];
  const int l = blockIdx.z, h0 = blockIdx.y * 64, i0 = blockIdx.x * 64;
  const int tid = threadIdx.x;
#pragma unroll
  for (int t = 0; t < 16; ++t) {
    const int e = t * 256 + tid;
    const int ii = e >> 6, hh = e & 63;
    tile[ii][hh] = lw1[(size_t)l * 98304 + (size_t)(i0 + ii) * 128 + (h0 + hh)];
  }
  __syncthreads();
#pragma unroll
  for (int t = 0; t < 16; ++t) {
    const int e = t * 256 + tid;
    const int hh = e >> 6, ii = e & 63;
    BT1[(size_t)(l * 128 + h0 + hh) * 768 + i0 + ii] = f2bf(tile[ii][hh]);
  }
}

// leaf_w2 (64,128,768) -> BT2[o][(l*128+h)] with row stride 8256
__global__ __launch_bounds__(256)
void cvt_bt2_k(const float* __restrict__ lw2, short* __restrict__ BT2) {
  __shared__ float tile[64][65];
  const int l = blockIdx.z, h0 = blockIdx.y * 64, o0 = blockIdx.x * 64;
  const int tid = threadIdx.x;
#pragma unroll
  for (int t = 0; t < 16; ++t) {
    const int e = t * 256 + tid;
    const int hh = e >> 6, oo = e & 63;
    tile[hh][oo] = lw2[(size_t)l * 98304 + (size_t)(h0 + hh) * 768 + (o0 + oo)];
  }
  __syncthreads();
#pragma unroll
  for (int t = 0; t < 16; ++t) {
    const int e = t * 256 + tid;
    const int oo = e >> 6, hh = e & 63;
    BT2[(size_t)(o0 + oo) * 8256 + l * 128 + h0 + hh] = f2bf(tile[hh][oo]);
  }
}

// leaf_b2 (64,768) -> BT2 extension columns [o][8192+l]
__global__ __launch_bounds__(256)
void cvt_b2e_k(const float* __restrict__ lb2, short* __restrict__ BT2) {
  const int idx = blockIdx.x * 256 + threadIdx.x;  // 768*64 = 49152
  const int o = idx >> 6, l = idx & 63;
  BT2[(size_t)o * 8256 + 8192 + l] = f2bf(lb2[(size_t)l * 768 + o]);
}

// ---------------- gate kernel ----------------
// hn: raw pre-activation node GEMM output (4096 x 1024, only 1008 cols valid)
__global__ __launch_bounds__(256)
void gates_k(const float* __restrict__ hn, const float* __restrict__ nb1,
             const float* __restrict__ nw2, const float* __restrict__ nb2,
             float* __restrict__ wgt, short* __restrict__ hs) {
  const int b = blockIdx.x * 4 + (threadIdx.x >> 6);
  const int lane = threadIdx.x & 63;
  float c = 0.f;
  if (lane < 63) {
    float s = nb2[lane];
    const float* h = hn + (size_t)b * 1024 + lane * 16;
#pragma unroll
    for (int j = 0; j < 16; ++j) {
      float v = fmaxf(h[j] + nb1[lane * 16 + j], 0.f);
      s += v * nw2[lane * 16 + j];
    }
    c = 1.f / (1.f + expf(-s));
  }
  float w = 1.f;
#pragma unroll
  for (int lvl = 0; lvl < 6; ++lvl) {
    const int idx = (1 << lvl) - 1 + (lane >> (6 - lvl));
    const float g = __shfl(c, idx, 64);
    w *= ((lane >> (5 - lvl)) & 1) ? (1.f - g) : g;
  }
  wgt[(size_t)b * 64 + lane] = w;
  hs[(size_t)b * 8256 + 8192 + lane] = f2bf(w);
}

// ---------------- GEMM: C = A(MxK) * B^T(NxK), bf16 in, f32 acc ----------------
// BN=128, BK=64, 256 threads = 4 waves (2x2), wave tile (BM/2)x64.
// EPI 0: store f32 raw. EPI 1: bf16 store of relu(acc + bias[col]) * wgt[row][n0>>7].
template <int BM, int EPI>
__global__ __launch_bounds__(256, 2)
void gemm_bt(const short* __restrict__ A, const short* __restrict__ B,
             void* __restrict__ Cv, int K, int lda, int ldb, int ldc,
             const float* __restrict__ bias, const float* __restrict__ wgt) {
  constexpr int BN = 128, BK = 64;
  constexpr int ABYTES = BM * BK * 2;
  constexpr int BBYTES = BN * BK * 2;
  constexpr int FM = BM / 32;
  __shared__ char lds[2 * (ABYTES + BBYTES)];

  const int tid = threadIdx.x;
  const int lane = tid & 63;
  const int wid = tid >> 6;
  const int wm = wid >> 1, wn = wid & 1;
  const int m0 = blockIdx.y * BM;
  const int n0 = blockIdx.x * BN;

  f32x4 acc[FM][4];
  const f32x4 zero = {0.f, 0.f, 0.f, 0.f};
#pragma unroll
  for (int i = 0; i < FM; ++i)
#pragma unroll
    for (int j = 0; j < 4; ++j) acc[i][j] = zero;

  const int KT = K / BK;

  auto stage = [&](int buf, int kt) {
    const int k0 = kt * BK;
    char* ldsA = lds + buf * (ABYTES + BBYTES);
    char* ldsB = ldsA + ABYTES;
#pragma unroll
    for (int q = 0; q < BM / 32; ++q) {
      const int off = q * 4096 + tid * 16;
      const int r = off >> 7;
      const int cs = ((off >> 4) & 7) ^ (r & 7);  // source chunk (inverse swizzle)
      gload16(A + (size_t)(m0 + r) * lda + k0 + cs * 8, ldsA + off);
    }
#pragma unroll
    for (int q = 0; q < 4; ++q) {
      const int off = q * 4096 + tid * 16;
      const int r = off >> 7;
      const int cs = ((off >> 4) & 7) ^ (r & 7);
      gload16(B + (size_t)(n0 + r) * ldb + k0 + cs * 8, ldsB + off);
    }
  };

  stage(0, 0);
  for (int kt = 0; kt < KT; ++kt) {
    const int buf = kt & 1;
    __syncthreads();  // drains vmcnt+lgkmcnt, then barrier: tile[buf] ready, prev reads done
    if (kt + 1 < KT) stage(buf ^ 1, kt + 1);
    const char* ldsA = lds + buf * (ABYTES + BBYTES);
    const char* ldsB = ldsA + ABYTES;
#pragma unroll
    for (int kk = 0; kk < 2; ++kk) {
      const int chunk = (kk * 32 + 8 * (lane >> 4)) >> 3;  // 16B chunk index in row
      short8 af[FM], bfr[4];
#pragma unroll
      for (int i = 0; i < FM; ++i) {
        const int row = wm * (BM / 2) + i * 16 + (lane & 15);
        af[i] = *(const short8*)(ldsA + row * 128 + ((chunk ^ (row & 7)) << 4));
      }
#pragma unroll
      for (int j = 0; j < 4; ++j) {
        const int row = wn * 64 + j * 16 + (lane & 15);
        bfr[j] = *(const short8*)(ldsB + row * 128 + ((chunk ^ (row & 7)) << 4));
      }
#pragma unroll
      for (int i = 0; i < FM; ++i)
#pragma unroll
        for (int j = 0; j < 4; ++j)
          acc[i][j] = __builtin_amdgcn_mfma_f32_16x16x32_bf16(af[i], bfr[j], acc[i][j], 0, 0, 0);
    }
  }

  const int row_base = m0 + wm * (BM / 2) + (lane >> 4) * 4;
  const int col_base = n0 + wn * 64 + (lane & 15);
  if constexpr (EPI == 1) {
    short* C = (short*)Cv;
    const int leaf = n0 >> 7;  // BN==128: one leaf per column tile
#pragma unroll
    for (int i = 0; i < FM; ++i)
#pragma unroll
      for (int j = 0; j < 4; ++j) {
        const int col = col_base + j * 16;
        const float b = bias[col];
#pragma unroll
        for (int r = 0; r < 4; ++r) {
          const int row = row_base + i * 16 + r;
          const float v = fmaxf(acc[i][j][r] + b, 0.f) * wgt[(size_t)row * 64 + leaf];
          C[(size_t)row * ldc + col] = f2bf(v);
        }
      }
  } else {
    float* C = (float*)Cv;
#pragma unroll
    for (int i = 0; i < FM; ++i)
#pragma unroll
      for (int j = 0; j < 4; ++j) {
        const int col = col_base + j * 16;
#pragma unroll
        for (int r = 0; r < 4; ++r) {
          const int row = row_base + i * 16 + r;
          C[(size_t)row * ldc + col] = acc[i][j][r];
        }
      }
  }
}

// ---------------- launch ----------------

extern "C" void kernel_launch(void* const* d_in, const int* in_sizes, int n_in,
                              void* d_out, int out_size, void* d_ws, size_t ws_size,
                              hipStream_t stream) {
  const float* x   = (const float*)d_in[0];
  const float* nw1 = (const float*)d_in[1];
  const float* nb1 = (const float*)d_in[2];
  const float* nw2 = (const float*)d_in[3];
  const float* nb2 = (const float*)d_in[4];
  const float* lw1 = (const float*)d_in[5];
  const float* lb1 = (const float*)d_in[6];
  const float* lw2 = (const float*)d_in[7];
  const float* lb2 = (const float*)d_in[8];

  char* ws = (char*)d_ws;
  // layout (bytes):
  short* xb  = (short*)(ws + 0);         // 4096*768*2   = 6,291,456
  short* BTn = (short*)(ws + 6291456);   // 1024*768*2   = 1,572,864
  short* BT1 = (short*)(ws + 7864320);   // 8192*768*2   = 12,582,912
  short* BT2 = (short*)(ws + 20447232);  // 768*8256*2   = 12,681,216
  float* hn  = (float*)(ws + 33128448);  // 4096*1024*4  = 16,777,216
  float* wgt = (float*)(ws + 49905664);  // 4096*64*4    = 1,048,576
  short* hs  = (short*)(ws + 50954240);  // 4096*8256*2  = 67,633,152  (end ~118.6 MB)

  // 1. dtype conversions / layout permutes
  cvt_x_k<<<3072, 256, 0, stream>>>(x, xb);
  cvt_btn_k<<<3072, 256, 0, stream>>>(nw1, BTn);
  cvt_bt1_k<<<dim3(12, 2, 64), 256, 0, stream>>>(lw1, BT1);
  cvt_bt2_k<<<dim3(12, 2, 64), 256, 0, stream>>>(lw2, BT2);
  cvt_b2e_k<<<192, 256, 0, stream>>>(lb2, BT2);

  // 2. node GEMM: hn = xb @ BTn^T  (4096 x 1024, K=768), raw f32
  gemm_bt<128, 0><<<dim3(8, 32), 256, 0, stream>>>(xb, BTn, hn, 768, 768, 768, 1024,
                                                   nullptr, nullptr);
  // 3. gates: c = sigmoid(relu(hn+b1)@w2 + b2); w = prod over tree path; also hs K-ext cols
  gates_k<<<1024, 256, 0, stream>>>(hn, nb1, nw2, nb2, wgt, hs);

  // 4. hs = bf16( relu(xb @ BT1^T + b1) * w[leaf] )   (4096 x 8192, K=768)
  gemm_bt<128, 1><<<dim3(64, 32), 256, 0, stream>>>(xb, BT1, hs, 768, 768, 768, 8256,
                                                    lb1, wgt);
  // 5. out = hs @ BT2^T   (4096 x 768, K=8256; leaf_b2 folded in via K-extension)
  gemm_bt<64, 0><<<dim3(6, 64), 256, 0, stream>>>(hs, BT2, (float*)d_out, 8256, 8256,
                                                  8256, 768, nullptr, nullptr);
}

// Round 2
// 191.395 us; speedup vs baseline: 1.0917x; 1.0917x over previous
//
#include <hip/hip_runtime.h>
#include <stdint.h>
#include <stddef.h>

typedef __attribute__((ext_vector_type(8))) short short8;
typedef __attribute__((ext_vector_type(4))) float f32x4;
typedef __attribute__((ext_vector_type(4))) short short4v;

__device__ __forceinline__ short f2bf(float f) {
  unsigned u = __builtin_bit_cast(unsigned, f);
  u = (u + 0x7fffu + ((u >> 16) & 1u)) >> 16;
  return (short)u;
}

__device__ __forceinline__ void gload16(const void* g, void* l) {
  __builtin_amdgcn_global_load_lds(
      (const __attribute__((address_space(1))) unsigned int*)g,
      (__attribute__((address_space(3))) unsigned int*)l, 16, 0, 0);
}

// ---------------- conversion kernels (merged) ----------------

// blocks [0,3072): x f32->bf16 (float4/thread)
// blocks [3072,6144): node_w1 (63,768,16) -> BTn[(n*16+h)][i], zero-padded to 1024 rows
// blocks [6144,6336): leaf_b2 (64,768) -> BT2 K-extension cols [o][8192+l]
__global__ __launch_bounds__(256)
void cvt_misc_k(const float* __restrict__ x, const float* __restrict__ nw1,
                const float* __restrict__ lb2, short* __restrict__ xb,
                short* __restrict__ BTn, short* __restrict__ BT2) {
  const int bx = blockIdx.x;
  if (bx < 3072) {
    const int i = bx * 256 + threadIdx.x;
    const float4 v = ((const float4*)x)[i];
    short4v o;
    o.x = f2bf(v.x); o.y = f2bf(v.y); o.z = f2bf(v.z); o.w = f2bf(v.w);
    *(short4v*)(xb + (size_t)i * 4) = o;
  } else if (bx < 6144) {
    const int idx = (bx - 3072) * 256 + threadIdx.x;  // 1024*768
    const int i = idx % 768;
    const int nh = idx / 768;
    float v = 0.f;
    if (nh < 1008) v = nw1[((size_t)(nh >> 4) * 768 + i) * 16 + (nh & 15)];
    BTn[idx] = f2bf(v);
  } else {
    const int idx = (bx - 6144) * 256 + threadIdx.x;  // 768*64
    const int o = idx >> 6, l = idx & 63;
    BT2[(size_t)o * 8256 + 8192 + l] = f2bf(lb2[(size_t)l * 768 + o]);
  }
}

// z<64: leaf_w1 (64,768,128) -> BT1[(l*128+h)][i]
// z>=64: leaf_w2 (64,128,768) -> BT2[o][(l*128+h)], row stride 8256
__global__ __launch_bounds__(256)
void cvt_w_k(const float* __restrict__ lw1, const float* __restrict__ lw2,
             short* __restrict__ BT1, short* __restrict__ BT2) {
  __shared__ float tile[64][65];
  const int tid = threadIdx.x;
  if (blockIdx.z < 64) {
    const int l = blockIdx.z, h0 = blockIdx.y * 64, i0 = blockIdx.x * 64;
#pragma unroll
    for (int t = 0; t < 16; ++t) {
      const int e = t * 256 + tid;
      const int ii = e >> 6, hh = e & 63;
      tile[ii][hh] = lw1[(size_t)l * 98304 + (size_t)(i0 + ii) * 128 + (h0 + hh)];
    }
    __syncthreads();
#pragma unroll
    for (int t = 0; t < 16; ++t) {
      const int e = t * 256 + tid;
      const int hh = e >> 6, ii = e & 63;
      BT1[(size_t)(l * 128 + h0 + hh) * 768 + i0 + ii] = f2bf(tile[ii][hh]);
    }
  } else {
    const int l = blockIdx.z - 64, h0 = blockIdx.y * 64, o0 = blockIdx.x * 64;
#pragma unroll
    for (int t = 0; t < 16; ++t) {
      const int e = t * 256 + tid;
      const int hh = e >> 6, oo = e & 63;
      tile[hh][oo] = lw2[(size_t)l * 98304 + (size_t)(h0 + hh) * 768 + (o0 + oo)];
    }
    __syncthreads();
#pragma unroll
    for (int t = 0; t < 16; ++t) {
      const int e = t * 256 + tid;
      const int oo = e >> 6, hh = e & 63;
      BT2[(size_t)(o0 + oo) * 8256 + l * 128 + h0 + hh] = f2bf(tile[hh][oo]);
    }
  }
}

// ---------------- gate kernel ----------------
__global__ __launch_bounds__(256)
void gates_k(const float* __restrict__ hn, const float* __restrict__ nb1,
             const float* __restrict__ nw2, const float* __restrict__ nb2,
             float* __restrict__ wgt, short* __restrict__ hs) {
  const int b = blockIdx.x * 4 + (threadIdx.x >> 6);
  const int lane = threadIdx.x & 63;
  float c = 0.f;
  if (lane < 63) {
    float s = nb2[lane];
    const float* h = hn + (size_t)b * 1024 + lane * 16;
#pragma unroll
    for (int j = 0; j < 16; ++j) {
      float v = fmaxf(h[j] + nb1[lane * 16 + j], 0.f);
      s += v * nw2[lane * 16 + j];
    }
    c = 1.f / (1.f + expf(-s));
  }
  float w = 1.f;
#pragma unroll
  for (int lvl = 0; lvl < 6; ++lvl) {
    const int idx = (1 << lvl) - 1 + (lane >> (6 - lvl));
    const float g = __shfl(c, idx, 64);
    w *= ((lane >> (5 - lvl)) & 1) ? (1.f - g) : g;
  }
  wgt[(size_t)b * 64 + lane] = w;
  hs[(size_t)b * 8256 + 8192 + lane] = f2bf(w);
}

// ---------------- GEMM: C = A(MxK) * B^T(NxK), bf16 in, f32 acc ----------------
// Flat 1D grid with XCD-chunk swizzle; decompose sid -> (x=N-tile, y=M-tile, z=K-split).
// EPI 0: f32 store to {Cv, P1, P2}[z]. EPI 1: bf16 relu(acc+bias[col])*wgt[row][leaf].
template <int BM, int EPI>
__global__ __launch_bounds__(256, (BM == 64 ? 3 : 2))
void gemm_bt(const short* __restrict__ A, const short* __restrict__ B,
             void* __restrict__ Cv, float* __restrict__ P1, float* __restrict__ P2,
             int ktn, int lda, int ldb, int ldc, int nx, int ny,
             const float* __restrict__ bias, const float* __restrict__ wgt) {
  constexpr int BN = 128, BK = 64;
  constexpr int ABYTES = BM * BK * 2;
  constexpr int BBYTES = BN * BK * 2;
  constexpr int FM = BM / 32;
  __shared__ char lds[2 * (ABYTES + BBYTES)];

  const int tid = threadIdx.x;
  const int lane = tid & 63;
  const int wid = tid >> 6;
  const int wm = wid >> 1, wn = wid & 1;

  // XCD-chunked bijective swizzle (gridDim.x % 8 == 0 for all launches)
  const int cpx = gridDim.x >> 3;
  const int bid = blockIdx.x;
  const int sid = (bid & 7) * cpx + (bid >> 3);
  const int xg = sid % nx;
  const int t1 = sid / nx;
  const int yg = t1 % ny;
  const int z = t1 / ny;
  const int m0 = yg * BM;
  const int n0 = xg * BN;
  const int kt0 = z * ktn;

  f32x4 acc[FM][4];
  const f32x4 zero = {0.f, 0.f, 0.f, 0.f};
#pragma unroll
  for (int i = 0; i < FM; ++i)
#pragma unroll
    for (int j = 0; j < 4; ++j) acc[i][j] = zero;

  auto stage = [&](int buf, int kt) {
    const int k0 = kt * BK;
    char* ldsA = lds + buf * (ABYTES + BBYTES);
    char* ldsB = ldsA + ABYTES;
#pragma unroll
    for (int q = 0; q < BM / 32; ++q) {
      const int off = q * 4096 + tid * 16;
      const int r = off >> 7;
      const int cs = ((off >> 4) & 7) ^ (r & 7);  // inverse-swizzled source chunk
      gload16(A + (size_t)(m0 + r) * lda + k0 + cs * 8, ldsA + off);
    }
#pragma unroll
    for (int q = 0; q < 4; ++q) {
      const int off = q * 4096 + tid * 16;
      const int r = off >> 7;
      const int cs = ((off >> 4) & 7) ^ (r & 7);
      gload16(B + (size_t)(n0 + r) * ldb + k0 + cs * 8, ldsB + off);
    }
  };

  stage(0, kt0);
  for (int ki = 0; ki < ktn; ++ki) {
    const int buf = ki & 1;
    __syncthreads();  // drains vmcnt+lgkmcnt then barrier: tile[buf] ready, prev reads done
    if (ki + 1 < ktn) stage(buf ^ 1, kt0 + ki + 1);
    const char* ldsA = lds + buf * (ABYTES + BBYTES);
    const char* ldsB = ldsA + ABYTES;
#pragma unroll
    for (int kk = 0; kk < 2; ++kk) {
      const int chunk = (kk * 32 + 8 * (lane >> 4)) >> 3;
      short8 af[FM], bfr[4];
#pragma unroll
      for (int i = 0; i < FM; ++i) {
        const int row = wm * (BM / 2) + i * 16 + (lane & 15);
        af[i] = *(const short8*)(ldsA + row * 128 + ((chunk ^ (row & 7)) << 4));
      }
#pragma unroll
      for (int j = 0; j < 4; ++j) {
        const int row = wn * 64 + j * 16 + (lane & 15);
        bfr[j] = *(const short8*)(ldsB + row * 128 + ((chunk ^ (row & 7)) << 4));
      }
#pragma unroll
      for (int i = 0; i < FM; ++i)
#pragma unroll
        for (int j = 0; j < 4; ++j)
          acc[i][j] = __builtin_amdgcn_mfma_f32_16x16x32_bf16(af[i], bfr[j], acc[i][j], 0, 0, 0);
    }
  }

  const int row_base = m0 + wm * (BM / 2) + (lane >> 4) * 4;
  const int col_base = n0 + wn * 64 + (lane & 15);
  if constexpr (EPI == 1) {
    short* C = (short*)Cv;
    const int leaf = n0 >> 7;
#pragma unroll
    for (int i = 0; i < FM; ++i)
#pragma unroll
      for (int j = 0; j < 4; ++j) {
        const int col = col_base + j * 16;
        const float b = bias[col];
#pragma unroll
        for (int r = 0; r < 4; ++r) {
          const int row = row_base + i * 16 + r;
          const float v = fmaxf(acc[i][j][r] + b, 0.f) * wgt[(size_t)row * 64 + leaf];
          C[(size_t)row * ldc + col] = f2bf(v);
        }
      }
  } else {
    float* C = (z == 0) ? (float*)Cv : (z == 1 ? P1 : P2);
#pragma unroll
    for (int i = 0; i < FM; ++i)
#pragma unroll
      for (int j = 0; j < 4; ++j) {
        const int col = col_base + j * 16;
#pragma unroll
        for (int r = 0; r < 4; ++r) {
          const int row = row_base + i * 16 + r;
          C[(size_t)row * ldc + col] = acc[i][j][r];
        }
      }
  }
}

// ---------------- split-K reduce: out += p1 + p2 ----------------
__global__ __launch_bounds__(256)
void reduce_k(float* __restrict__ out, const float* __restrict__ p1,
              const float* __restrict__ p2) {
  const int i = blockIdx.x * 256 + threadIdx.x;  // 786432 threads, f32x4 each
  f32x4 a = ((const f32x4*)out)[i];
  f32x4 b = ((const f32x4*)p1)[i];
  f32x4 c = ((const f32x4*)p2)[i];
  ((f32x4*)out)[i] = a + b + c;
}

// ---------------- launch ----------------

extern "C" void kernel_launch(void* const* d_in, const int* in_sizes, int n_in,
                              void* d_out, int out_size, void* d_ws, size_t ws_size,
                              hipStream_t stream) {
  const float* x   = (const float*)d_in[0];
  const float* nw1 = (const float*)d_in[1];
  const float* nb1 = (const float*)d_in[2];
  const float* nw2 = (const float*)d_in[3];
  const float* nb2 = (const float*)d_in[4];
  const float* lw1 = (const float*)d_in[5];
  const float* lb1 = (const float*)d_in[6];
  const float* lw2 = (const float*)d_in[7];
  const float* lb2 = (const float*)d_in[8];

  char* ws = (char*)d_ws;
  // layout (bytes):
  short* xb  = (short*)(ws + 0);         // 4096*768*2   = 6,291,456   (dead after gemm1)
  short* BTn = (short*)(ws + 6291456);   // 1024*768*2   = 1,572,864   (dead after node gemm)
  short* BT1 = (short*)(ws + 7864320);   // 8192*768*2   = 12,582,912  (dead after gemm1)
  short* BT2 = (short*)(ws + 20447232);  // 768*8256*2   = 12,681,216  (live in gemm2)
  float* hn  = (float*)(ws + 33128448);  // 4096*1024*4  = 16,777,216  (dead after gates)
  float* wgt = (float*)(ws + 49905664);  // 4096*64*4    = 1,048,576   (dead after gemm1)
  short* hs  = (short*)(ws + 50954240);  // 4096*8256*2  = 67,633,152  (live in gemm2)
  // split-K partials alias dead regions during gemm2:
  float* p1  = (float*)(ws + 0);         // 4096*768*4 = 12,582,912  (over xb+BTn+BT1 head)
  float* p2  = (float*)(ws + 33128448);  // 12,582,912               (over hn)

  // 1. conversions (merged)
  cvt_misc_k<<<6336, 256, 0, stream>>>(x, nw1, lb2, xb, BTn, BT2);
  cvt_w_k<<<dim3(12, 2, 128), 256, 0, stream>>>(lw1, lw2, BT1, BT2);

  // 2. node GEMM: hn = xb @ BTn^T (4096x1024, K=768) raw f32
  gemm_bt<64, 0><<<512, 256, 0, stream>>>(xb, BTn, hn, nullptr, nullptr,
                                          12, 768, 768, 1024, 8, 64, nullptr, nullptr);
  // 3. gates
  gates_k<<<1024, 256, 0, stream>>>(hn, nb1, nw2, nb2, wgt, hs);

  // 4. hs = bf16(relu(xb @ BT1^T + b1) * w[leaf])  (4096x8192, K=768)
  gemm_bt<128, 1><<<2048, 256, 0, stream>>>(xb, BT1, hs, nullptr, nullptr,
                                            12, 768, 768, 8256, 64, 32, lb1, wgt);

  // 5. out = hs @ BT2^T (4096x768, K=8256; bias folded via K-extension), split-K=3
  gemm_bt<64, 0><<<1152, 256, 0, stream>>>(hs, BT2, (float*)d_out, p1, p2,
                                           43, 8256, 8256, 768, 6, 64, nullptr, nullptr);
  // 6. out += p1 + p2
  reduce_k<<<3072, 256, 0, stream>>>((float*)d_out, p1, p2);
}